// Round 8
// baseline (677.328 us; speedup 1.0000x reference)
//
#include <hip/hip_runtime.h>
#include <math.h>

#define GRID 256
#define NTHR 256
static const int Bb = 32, Ls = 512, Dd = 768, Cc = 97;

struct KArgs {
    const float *x0, *pos1, *pos2;
    const int* mask;
    const float *emb, *rel_w, *rel_b, *kw, *vw, *vb, *sw, *gw, *gb;
    const float *fc1w, *fc1b, *fc2w, *fc2b;
    float* out;
    float *p0b, *pp, *sc, *avx1, *avx2, *av1, *av2, *aw1, *aw2, *S0, *S1, *xp1, *xp2, *geb;
    float *kvecs, *pdots, *g1buf, *xd, *gx1, *gx2, *awb;
    int* bar;
    float* zbase;
    int zcount;
};

__device__ __forceinline__ float sigm(float x) { return 1.f / (1.f + expf(-x)); }

__device__ __forceinline__ float wred(float v) {
#pragma unroll
    for (int o = 32; o > 0; o >>= 1) v += __shfl_down(v, o, 64);
    return v;
}

__device__ __forceinline__ float blk_sum4(float v, float* shr) {
    v = wred(v);
    int t = threadIdx.x;
    if ((t & 63) == 0) shr[t >> 6] = v;
    __syncthreads();
    float r = shr[0] + shr[1] + shr[2] + shr[3];
    __syncthreads();
    return r;
}

// ---- software grid barrier (sense-reversal, device-scope atomics).
// Grid=256 blocks @ 256 thr, ~9KB LDS: all blocks structurally co-resident (1/CU).
__device__ void gbar(int* bar, int epoch) {
    __syncthreads();
    if (threadIdx.x == 0) {
        __threadfence();                        // release: publish this block's writes
        int old = atomicAdd(&bar[0], 1);
        if (old == GRID - 1) {
            bar[0] = 0;
            __threadfence();
            atomicExch(&bar[1], epoch);         // release epoch
        } else {
            while (atomicAdd(&bar[1], 0) < epoch) __builtin_amdgcn_s_sleep(1);
        }
        __threadfence();                        // acquire: see other blocks' writes
    }
    __syncthreads();
}

// ---- split-K SGEMM tile: C += A[:,kb:kb+KC]@W[kb:kb+KC,:] (+bias at bz==0); C pre-zeroed
__device__ void sgemm_dev(const float* __restrict__ A, const float* __restrict__ W,
                          const float* __restrict__ bias, float* __restrict__ C,
                          int M, int N, int K, int KC, int bx, int by, int bz,
                          float* As, float* Ws) {
    int tid = threadIdx.x;
    int tx = tid & 15, ty = tid >> 4;
    int bn = bx * 64, bm = by * 64;
    int kb = bz * KC;
    int arow = tid >> 2, akq = (tid & 3) << 2;
    int wrow = tid >> 4, wcol = (tid & 15) << 2;
    int gar = bm + arow;
    bool aval = gar < M;
    const float* Ap = A + (size_t)gar * K + kb + akq;
    const float* Wp = W + (size_t)(kb + wrow) * N + bn + wcol;
    float acc[4][4] = {{0.f}};
    float4 a4 = make_float4(0.f, 0.f, 0.f, 0.f);
    if (aval) a4 = *(const float4*)Ap;
    float4 w4 = *(const float4*)Wp;
    for (int k0 = 0; k0 < KC; k0 += 16) {
        __syncthreads();
        As[(akq + 0) * 64 + arow] = a4.x; As[(akq + 1) * 64 + arow] = a4.y;
        As[(akq + 2) * 64 + arow] = a4.z; As[(akq + 3) * 64 + arow] = a4.w;
        *(float4*)&Ws[wrow * 64 + wcol] = w4;
        __syncthreads();
        if (k0 + 16 < KC) {
            if (aval) a4 = *(const float4*)(Ap + k0 + 16);
            w4 = *(const float4*)(Wp + (size_t)(k0 + 16) * N);
        }
#pragma unroll
        for (int kk = 0; kk < 16; ++kk) {
            float4 a = *(const float4*)&As[kk * 64 + (ty << 2)];
            float4 b = *(const float4*)&Ws[kk * 64 + (tx << 2)];
            acc[0][0]+=a.x*b.x; acc[0][1]+=a.x*b.y; acc[0][2]+=a.x*b.z; acc[0][3]+=a.x*b.w;
            acc[1][0]+=a.y*b.x; acc[1][1]+=a.y*b.y; acc[1][2]+=a.y*b.z; acc[1][3]+=a.y*b.w;
            acc[2][0]+=a.z*b.x; acc[2][1]+=a.z*b.y; acc[2][2]+=a.z*b.z; acc[2][3]+=a.z*b.w;
            acc[3][0]+=a.w*b.x; acc[3][1]+=a.w*b.y; acc[3][2]+=a.w*b.z; acc[3][3]+=a.w*b.w;
        }
    }
    int gc = bn + (tx << 2);
    float4 bz4 = make_float4(0.f, 0.f, 0.f, 0.f);
    if (bz == 0 && bias) bz4 = *(const float4*)(bias + gc);
#pragma unroll
    for (int i = 0; i < 4; ++i) {
        int gr = bm + (ty << 2) + i;
        if (gr < M) {
            float* cp = C + (size_t)gr * N + gc;
            atomicAdd(cp + 0, acc[i][0] + bz4.x); atomicAdd(cp + 1, acc[i][1] + bz4.y);
            atomicAdd(cp + 2, acc[i][2] + bz4.z); atomicAdd(cp + 3, acc[i][3] + bz4.w);
        }
    }
    __syncthreads();
}

// ---- fused relation-attention + V-GEMV bank; jlin in [0,768)
__device__ void attn_gemv(const KArgs& a, int phase, int jlin,
                          float* xs, float* lw, float* shr) {
    int t = threadIdx.x;
    int jt = jlin % 3, b = (jlin / 3) % 32, kseg = jlin / 96;
    float v = -3.0e38f, g1 = 0.f;
    if (t < Cc) {
        if (phase == 0) v = a.pdots[t];
        else {
            g1 = sigm(a.pdots[194 + t] + a.sc[128 + b] + a.gb[1]);
            v = 2.f * a.pdots[97 + t] + g1 * a.sc[160 + b];
        }
    }
    if (phase == 1 && jt == 0 && kseg == 0 && t < Cc) a.g1buf[(size_t)b * Cc + t] = g1;
    float m = v;
#pragma unroll
    for (int o = 32; o > 0; o >>= 1) m = fmaxf(m, __shfl_down(m, o, 64));
    if ((t & 63) == 0) shr[t >> 6] = m;
    __syncthreads();
    m = fmaxf(fmaxf(shr[0], shr[1]), fmaxf(shr[2], shr[3]));
    __syncthreads();
    float e = (t < Cc) ? expf(v - m) : 0.f;
    float s = blk_sum4(e, shr);
    float wc = e / s;
    if (t < Cc) lw[t] = wc;
    float cg1 = blk_sum4(wc * g1, shr);   // publishes lw
    float alpha = (phase == 0) ? 1.f : 2.f;
    if (t < 96) {
        int d = kseg * 96 + t;
        const float* pc = a.p0b + d;
        float acc2 = 0.f;
#pragma unroll 4
        for (int c = 0; c < Cc; ++c) acc2 += lw[c] * pc[(size_t)c * Dd];
        float val = alpha * acc2;
        if (phase == 1) val += cg1 * a.av1[(size_t)b * Dd + d];
        xs[t] = val;
    }
    __syncthreads();
    const float* W = a.vw + (size_t)(phase == 0 ? 0 : 2) * Dd * Dd;
    const float* bias = a.vb + (phase == 0 ? 0 : 2) * Dd;
    float* outp = (phase == 0) ? a.avx1 : a.avx2;
    int j = jt * 256 + t;
    float acc = (kseg == 0) ? bias[j] : 0.f;
    const float* wp = W + (size_t)(kseg * 96) * Dd + j;
#pragma unroll 8
    for (int dd = 0; dd < 96; ++dd) acc += xs[dd] * wp[(size_t)dd * Dd];
    atomicAdd(&outp[(size_t)b * Dd + j], acc);
    const float* da[4]; const float* db[4]; int nd; float* dout;
    if (phase == 0) {
        da[0]=a.gw;          db[0]=nullptr;
        da[1]=a.kvecs+Dd;    db[1]=nullptr;
        da[2]=a.gw+3072;     db[2]=a.gw+3840;
        da[3]=a.kvecs+3*Dd;  db[3]=nullptr;
        nd = 4; dout = a.sc;
    } else {
        da[0]=a.gw+3072;     db[0]=nullptr;
        da[1]=a.kvecs+3*Dd;  db[1]=nullptr;
        nd = 2; dout = a.sc + 224;
    }
    for (int vv = 0; vv < nd; ++vv) {
        float wv = da[vv][j] + (db[vv] ? db[vv][j] : 0.f);
        float p = blk_sum4(acc * wv, shr);
        if (t == 0) atomicAdd(&dout[vv * 32 + b], p);
    }
    __syncthreads();
}

// ---- GEMV bank: out[b,:] += xs@Wseg
__device__ void mm_dev(const KArgs& a, int jlin, const float* S, float gamma,
                       const float* avA, const float* coefA, float multA,
                       const float* avB, const float* coefB, float multB,
                       const float* W, const float* bias, float* outp,
                       int ndots, const float* d0a, const float* d0b,
                       const float* d1a, const float* d2a, const float* d2b,
                       float* dout, float* xs, float* shr) {
    int t = threadIdx.x;
    int jt = jlin % 3, b = (jlin / 3) % 32, kseg = jlin / 96;
    if (t < 96) {
        int d = kseg * 96 + t;
        float v = gamma * S[(size_t)b * Dd + d];
        if (avA) v += multA * coefA[b] * avA[(size_t)b * Dd + d];
        if (avB) v += multB * coefB[b] * avB[(size_t)b * Dd + d];
        xs[t] = v;
    }
    __syncthreads();
    int j = jt * 256 + t;
    float acc = (kseg == 0 && bias) ? bias[j] : 0.f;
    const float* wp = W + (size_t)(kseg * 96) * Dd + j;
#pragma unroll 8
    for (int dd = 0; dd < 96; ++dd) acc += xs[dd] * wp[(size_t)dd * Dd];
    atomicAdd(&outp[(size_t)b * Dd + j], acc);
    if (ndots > 0) {
        float wv = d0a[j] + (d0b ? d0b[j] : 0.f);
        float p = blk_sum4(acc * wv, shr);
        if (t == 0) atomicAdd(&dout[b], p);
    }
    if (ndots > 1) {
        float p = blk_sum4(acc * d1a[j], shr);
        if (t == 0) atomicAdd(&dout[32 + b], p);
    }
    if (ndots > 2) {
        float wv = d2a[j] + (d2b ? d2b[j] : 0.f);
        float p = blk_sum4(acc * wv, shr);
        if (t == 0) atomicAdd(&dout[64 + b], p);
    }
    __syncthreads();
}

// ---- ge bank
__device__ void ge_dev(const KArgs& a, int jlin, float* xs, float* xs2) {
    int t = threadIdx.x;
    int jt = jlin % 3, b = (jlin / 3) % 32, kseg = jlin / 96;
    if (t < 96) {
        int d = kseg * 96 + t;
        float a1 = a.avx1[(size_t)b * Dd + d], a2 = a.avx2[(size_t)b * Dd + d];
        xs[t]  = (4.f * a.xp1[(size_t)b * Dd + d] + 2.f * a.sc[448 + b] * a1 + a.sc[480 + b] * a2) * a.sc[576 + b];
        xs2[t] = (4.f * a.xp2[(size_t)b * Dd + d] + 2.f * a.sc[512 + b] * a1 + a.sc[544 + b] * a2) * a.sc[608 + b];
    }
    __syncthreads();
    int j = jt * 256 + t;
    float a1 = 0.f, a2 = 0.f;
    const float* w1 = a.fc1w + (size_t)(Dd + kseg * 96) * Dd + j;
    const float* w2 = a.fc1w + (size_t)(2 * Dd + kseg * 96) * Dd + j;
#pragma unroll 8
    for (int dd = 0; dd < 96; ++dd) {
        a1 += xs[dd] * w1[(size_t)dd * Dd];
        a2 += xs2[dd] * w2[(size_t)dd * Dd];
    }
    float res = a1 + a2 + (kseg == 0 ? a.fc1b[j] : 0.f);
    atomicAdd(&a.geb[(size_t)b * Dd + j], res);
    __syncthreads();
}

// ---- dual bank sharing fc1w0
__device__ void aw_dual_dev(const KArgs& a, int jlin, float* xs, float* xs2) {
    int t = threadIdx.x;
    int jt = jlin % 3, b = (jlin / 3) % 32, kseg = jlin / 96;
    if (t < 96) {
        int d = kseg * 96 + t;
        xs[t]  = a.av1[(size_t)b * Dd + d];
        xs2[t] = a.av2[(size_t)b * Dd + d];
    }
    __syncthreads();
    int j = jt * 256 + t;
    float a1 = 0.f, a2 = 0.f;
    const float* wp = a.fc1w + (size_t)(kseg * 96) * Dd + j;
#pragma unroll 8
    for (int dd = 0; dd < 96; ++dd) {
        float w = wp[(size_t)dd * Dd];
        a1 += xs[dd] * w;
        a2 += xs2[dd] * w;
    }
    atomicAdd(&a.aw1[(size_t)b * Dd + j], a1);
    atomicAdd(&a.aw2[(size_t)b * Dd + j], a2);
    __syncthreads();
}

// ---- softgate
__device__ void softgate_dev(const KArgs& a, int phase, int b, float* shr) {
    int t = threadIdx.x;
    float ks[2], ga[2] = {0.f, 0.f}, gb2[2] = {0.f, 0.f};
#pragma unroll
    for (int i = 0; i < 2; ++i) {
        int l = t + (i << 8);
        size_t r = (size_t)b * Ls + l;
        float4 x = *(const float4*)(a.xd + r * 4);
        if (phase == 0) {
            float g = sigm(x.x + a.sc[b] + a.gb[0]);
            a.gx1[r] = g;
            ga[i] = g;
            ks[i] = 2.f * x.y + g * a.sc[32 + b];
        } else {
            float gp = a.gx1[r];
            float g = sigm(2.f * x.z + gp * a.sc[64 + b] + a.sc[224 + b] + a.gb[2]);
            a.gx2[r] = g;
            ga[i] = gp; gb2[i] = g;
            ks[i] = 4.f * x.w + 2.f * gp * a.sc[96 + b] + g * a.sc[256 + b];
        }
        if (a.mask[r] == 0) ks[i] = -1e9f;
    }
    float mx = fmaxf(ks[0], ks[1]);
#pragma unroll
    for (int o = 32; o > 0; o >>= 1) mx = fmaxf(mx, __shfl_down(mx, o, 64));
    if ((t & 63) == 0) shr[t >> 6] = mx;
    __syncthreads();
    mx = fmaxf(fmaxf(shr[0], shr[1]), fmaxf(shr[2], shr[3]));
    __syncthreads();
    float e0 = expf(ks[0] - mx), e1 = expf(ks[1] - mx);
    float s = blk_sum4(e0 + e1, shr);
    float inv = 1.f / s;
    float w0 = e0 * inv, w1 = e1 * inv;
    a.awb[(size_t)b * Ls + t] = w0;
    a.awb[(size_t)b * Ls + t + 256] = w1;
    float ca = blk_sum4(w0 * ga[0] + w1 * ga[1], shr);
    if (phase == 0) {
        if (t == 0) a.sc[320 + b] = ca;
    } else {
        if (t == 0) a.sc[352 + b] = ca;
        float cb = blk_sum4(w0 * gb2[0] + w1 * gb2[1], shr);
        if (t == 0) a.sc[384 + b] = cb;
        float q1a = a.pos1[(size_t)b * Ls + t], q1b = a.pos1[(size_t)b * Ls + t + 256];
        float q2a = a.pos2[(size_t)b * Ls + t], q2b = a.pos2[(size_t)b * Ls + t + 256];
        float s1 = blk_sum4(q1a + q1b, shr);
        float s2 = blk_sum4(q2a + q2b, shr);
        float c11 = blk_sum4(q1a * ga[0] + q1b * ga[1], shr);
        float c12 = blk_sum4(q1a * gb2[0] + q1b * gb2[1], shr);
        float c21 = blk_sum4(q2a * ga[0] + q2b * ga[1], shr);
        float c22 = blk_sum4(q2a * gb2[0] + q2b * gb2[1], shr);
        if (t == 0) {
            a.sc[448 + b] = c11; a.sc[480 + b] = c12;
            a.sc[512 + b] = c21; a.sc[544 + b] = c22;
            a.sc[576 + b] = 1.f / s1; a.sc[608 + b] = 1.f / s2;
        }
    }
    __syncthreads();
}

// ---- passX (float4 lanes, t<192; no syncthreads inside)
__device__ void passX_dev(const KArgs& a, int blk, float* S, bool dopos) {
    int t = threadIdx.x;
    if (t >= 192) return;
    int b = blk >> 4, seg = blk & 15, l0 = seg * 32;
    int d4 = t << 2;
    const float* xb = a.x0 + ((size_t)b * Ls + l0) * Dd + d4;
    const float* wb = a.awb + (size_t)b * Ls + l0;
    float4 as = make_float4(0.f,0.f,0.f,0.f);
    float4 a1 = make_float4(0.f,0.f,0.f,0.f);
    float4 a2 = make_float4(0.f,0.f,0.f,0.f);
    for (int l = 0; l < 32; ++l) {
        float4 xv = *(const float4*)(xb + (size_t)l * Dd);
        float wv = wb[l];
        as.x += wv*xv.x; as.y += wv*xv.y; as.z += wv*xv.z; as.w += wv*xv.w;
        if (dopos) {
            float q1 = a.pos1[(size_t)b * Ls + l0 + l], q2 = a.pos2[(size_t)b * Ls + l0 + l];
            a1.x += q1*xv.x; a1.y += q1*xv.y; a1.z += q1*xv.z; a1.w += q1*xv.w;
            a2.x += q2*xv.x; a2.y += q2*xv.y; a2.z += q2*xv.z; a2.w += q2*xv.w;
        }
    }
    float* ds = S + (size_t)b * Dd + d4;
    atomicAdd(ds+0, as.x); atomicAdd(ds+1, as.y); atomicAdd(ds+2, as.z); atomicAdd(ds+3, as.w);
    if (dopos) {
        float* d1 = a.xp1 + (size_t)b * Dd + d4;
        float* d2 = a.xp2 + (size_t)b * Dd + d4;
        atomicAdd(d1+0, a1.x); atomicAdd(d1+1, a1.y); atomicAdd(d1+2, a1.z); atomicAdd(d1+3, a1.w);
        atomicAdd(d2+0, a2.x); atomicAdd(d2+1, a2.y); atomicAdd(d2+2, a2.z); atomicAdd(d2+3, a2.w);
    }
}

// ---- init: zero accumulators + barrier state (ws re-poisoned to 0xAA each call)
__global__ __launch_bounds__(NTHR) void k_init(KArgs a) {
    size_t i = (size_t)blockIdx.x * NTHR + threadIdx.x;
    for (; i < (size_t)a.zcount; i += (size_t)512 * NTHR) a.zbase[i] = 0.f;
    if (blockIdx.x == 0 && threadIdx.x < 16) a.bar[threadIdx.x] = 0;
}

__global__ __launch_bounds__(NTHR) void mega(KArgs a) {
    __shared__ float As[1024], Ws[1024];
    __shared__ float xs[96], xs2[96];
    __shared__ float lw[128];
    __shared__ float shr[16];
    int blk = blockIdx.x, t = threadIdx.x;
    int wv_ = t >> 6, lane = t & 63;
    int wgid = blk * 4 + wv_;                 // 0..1023

    // ---- phase 0: kvecs (3072 wave-dots)
    for (int dot = wgid; dot < 3072; dot += 1024) {
        int idx = dot / Dd, d = dot - idx * Dd;
        const float* row = a.kw + ((size_t)idx * Dd + d) * Dd;
        const float* swk = a.sw + (size_t)idx * 2 * Dd + Dd;
        float sA = 0.f;
        for (int j = lane; j < Dd; j += 64) sA += row[j] * swk[j];
        sA = wred(sA);
        if (lane == 0) a.kvecs[dot] = sA;
    }
    gbar(a.bar, 1);

    // ---- phase 1: gemm1 (blocks 0..95, 2 jobs) || xdots (blocks 96..255)
    if (blk < 96) {
        for (int job = blk; job < 192; job += 96)
            sgemm_dev(a.emb, a.rel_w, a.rel_b, a.p0b, Cc, Dd, Dd, 96,
                      job % 12, (job / 12) % 2, job / 24, As, Ws);
    } else {
        float4 gs0[3], k1r[3], gs2[3], k3r[3];
#pragma unroll
        for (int k = 0; k < 3; ++k) {
            int d = (lane << 2) + k * 256;
            float4 ga = *(const float4*)(a.gw + d);
            float4 gbv = *(const float4*)(a.gw + 768 + d);
            gs0[k] = make_float4(ga.x+gbv.x, ga.y+gbv.y, ga.z+gbv.z, ga.w+gbv.w);
            k1r[k] = *(const float4*)(a.kvecs + 768 + d);
            float4 g2a = *(const float4*)(a.gw + 3072 + d);
            float4 g2b = *(const float4*)(a.gw + 3840 + d);
            gs2[k] = make_float4(g2a.x+g2b.x, g2a.y+g2b.y, g2a.z+g2b.z, g2a.w+g2b.w);
            k3r[k] = *(const float4*)(a.kvecs + 2304 + d);
        }
        int wloc = (blk - 96) * 4 + wv_;      // 0..639
        for (int r = wloc; r < Bb * Ls; r += 640) {
            const float* xr = a.x0 + (size_t)r * Dd;
            float s0 = 0.f, s1 = 0.f, s2 = 0.f, s3 = 0.f;
#pragma unroll
            for (int k = 0; k < 3; ++k) {
                float4 xv = *(const float4*)(xr + (lane << 2) + k * 256);
                s0 += xv.x*gs0[k].x + xv.y*gs0[k].y + xv.z*gs0[k].z + xv.w*gs0[k].w;
                s1 += xv.x*k1r[k].x + xv.y*k1r[k].y + xv.z*k1r[k].z + xv.w*k1r[k].w;
                s2 += xv.x*gs2[k].x + xv.y*gs2[k].y + xv.z*gs2[k].z + xv.w*gs2[k].w;
                s3 += xv.x*k3r[k].x + xv.y*k3r[k].y + xv.z*k3r[k].z + xv.w*k3r[k].w;
            }
            s0 = wred(s0); s1 = wred(s1); s2 = wred(s2); s3 = wred(s3);
            if (lane == 0) {
                float4 o4 = make_float4(s0, s1, s2, s3);
                *(float4*)(a.xd + (size_t)r * 4) = o4;
            }
        }
    }
    gbar(a.bar, 2);

    // ---- phase 2: pp gemm (0..95) || pdots (96..127)
    if (blk < 96) {
        sgemm_dev(a.p0b, a.fc1w, nullptr, a.pp, Cc, Dd, Dd, 192,
                  blk % 12, (blk / 12) % 2, blk / 24, As, Ws);
    } else if (blk < 128) {
        int wloc = (blk - 96) * 4 + wv_;      // 0..127
        for (int j = wloc; j < 388; j += 128) {
            int vv = j / Cc, r = j - vv * Cc;
            const float* va; const float* vb2 = nullptr;
            if (vv == 0) va = a.kvecs;
            else if (vv == 1) va = a.kvecs + 2 * Dd;
            else if (vv == 2) { va = a.gw + 1536; vb2 = a.gw + 2304; }
            else { va = a.gw + 4608; vb2 = a.gw + 5376; }
            const float* row = a.p0b + (size_t)r * Dd;
            float sA = 0.f;
            for (int jj = lane; jj < Dd; jj += 64)
                sA += row[jj] * (va[jj] + (vb2 ? vb2[jj] : 0.f));
            sA = wred(sA);
            if (lane == 0) a.pdots[j] = sA;
        }
    }
    gbar(a.bar, 3);

    // ---- phase 3: L0 RA1 attn+GEMV (768 jobs)
    for (int job = blk; job < 768; job += GRID) attn_gemv(a, 0, job, xs, lw, shr);
    gbar(a.bar, 4);

    // ---- phase 4: softgate L0
    if (blk < 32) softgate_dev(a, 0, blk, shr);
    gbar(a.bar, 5);

    // ---- phase 5: passX0 (512 jobs)
    for (int job = blk; job < 512; job += GRID) passX_dev(a, job, a.S0, true);
    gbar(a.bar, 6);

    // ---- phase 6: mm0 (768 jobs)
    for (int job = blk; job < 768; job += GRID)
        mm_dev(a, job, a.S0, 2.f, a.avx1, a.sc + 320, 1.f, nullptr, nullptr, 0.f,
               a.vw + (size_t)1 * Dd * Dd, a.vb + Dd, a.av1,
               3, a.gw + 1536, nullptr, a.kvecs + 2 * Dd, a.gw + 4608, a.gw + 5376,
               a.sc + 128, xs, shr);
    gbar(a.bar, 7);

    // ---- phase 7: L1 RA1 attn+GEMV
    for (int job = blk; job < 768; job += GRID) attn_gemv(a, 1, job, xs, lw, shr);
    gbar(a.bar, 8);

    // ---- phase 8: softgate L1 + pool coeffs
    if (blk < 32) softgate_dev(a, 1, blk, shr);
    gbar(a.bar, 9);

    // ---- phase 9: passX1 (512) || ge (768)
    for (int job = blk; job < 1280; job += GRID) {
        if (job < 512) passX_dev(a, job, a.S1, false);
        else ge_dev(a, job - 512, xs, xs2);
    }
    gbar(a.bar, 10);

    // ---- phase 10: mm1 (768)
    for (int job = blk; job < 768; job += GRID)
        mm_dev(a, job, a.S1, 4.f, a.avx1, a.sc + 352, 2.f, a.avx2, a.sc + 384, 1.f,
               a.vw + (size_t)3 * Dd * Dd, a.vb + 3 * Dd, a.av2,
               1, a.gw + 4608, nullptr, nullptr, nullptr, nullptr,
               a.sc + 288, xs, shr);
    gbar(a.bar, 11);

    // ---- phase 11: awdual (768)
    for (int job = blk; job < 768; job += GRID) aw_dual_dev(a, job, xs, xs2);
    gbar(a.bar, 12);

    // ---- phase 12: logits (3104 rows)
    for (int r = blk; r < Bb * Cc; r += GRID) {
        int b = r / Cc, c = r - b * Cc;
        float g1 = a.g1buf[r];
        float g2 = sigm(2.f * a.pdots[291 + c] + g1 * a.sc[192 + b] + a.sc[288 + b] + a.gb[3]);
        float ssum = 0.f;
#pragma unroll
        for (int sseg = 0; sseg < 3; ++sseg) {
            int d = t + sseg * 256;
            float h = tanhf(4.f * a.pp[(size_t)c * Dd + d]
                          + 2.f * g1 * a.aw1[(size_t)b * Dd + d]
                          + g2 * a.aw2[(size_t)b * Dd + d]
                          + a.geb[(size_t)b * Dd + d]);
            ssum += h * a.fc2w[d];
        }
        float tt = blk_sum4(ssum, shr);
        if (t == 0) a.out[r] = sigm(tt + a.fc2b[0]);
    }
    gbar(a.bar, 13);

    // ---- phase 13: argmax (first max)
    if (blk == 0 && t < Bb) {
        const float* row = a.out + (size_t)t * Cc;
        float best = row[0];
        int bi = 0;
        for (int c = 1; c < Cc; ++c) {
            float v = row[c];
            if (v > best) { best = v; bi = c; }
        }
        a.out[Bb * Cc + t] = (float)bi;
    }
}

extern "C" void kernel_launch(void* const* d_in, const int* in_sizes, int n_in,
                              void* d_out, int out_size, void* d_ws, size_t ws_size,
                              hipStream_t stream) {
    KArgs ka;
    ka.x0    = (const float*)d_in[0];
    ka.pos1  = (const float*)d_in[1];
    ka.pos2  = (const float*)d_in[2];
    ka.mask  = (const int*)d_in[3];
    ka.emb   = (const float*)d_in[4];
    ka.rel_w = (const float*)d_in[5];
    ka.rel_b = (const float*)d_in[6];
    // qw(7), qb(8) dead (softmax shift-invariance); kb(10), sb(14) dead (row-constant)
    ka.kw    = (const float*)d_in[9];
    ka.vw    = (const float*)d_in[11];
    ka.vb    = (const float*)d_in[12];
    ka.sw    = (const float*)d_in[13];
    ka.gw    = (const float*)d_in[15];
    ka.gb    = (const float*)d_in[16];
    ka.fc1w  = (const float*)d_in[17];
    ka.fc1b  = (const float*)d_in[18];
    ka.fc2w  = (const float*)d_in[19];
    ka.fc2b  = (const float*)d_in[20];
    ka.out   = (float*)d_out;

    float* ws = (float*)d_ws;
    size_t off = 0;
    const size_t PD = (size_t)Cc * Dd;
    const size_t BD = (size_t)Bb * Dd;
    ka.p0b  = ws + off; off += PD;
    ka.pp   = ws + off; off += PD;
    ka.sc   = ws + off; off += 640;
    ka.avx1 = ws + off; off += BD;
    ka.avx2 = ws + off; off += BD;
    ka.av1  = ws + off; off += BD;
    ka.av2  = ws + off; off += BD;
    ka.aw1  = ws + off; off += BD;
    ka.aw2  = ws + off; off += BD;
    ka.S0   = ws + off; off += BD;
    ka.S1   = ws + off; off += BD;
    ka.xp1  = ws + off; off += BD;
    ka.xp2  = ws + off; off += BD;
    ka.geb  = ws + off; off += BD;
    ka.zbase = ws;
    ka.zcount = (int)off;
    ka.bar   = (int*)(ws + off); off += 16;
    ka.kvecs = ws + off; off += (size_t)4 * Dd;
    ka.pdots = ws + off; off += 388;
    ka.g1buf = ws + off; off += (size_t)Bb * Cc;
    ka.xd    = ws + off; off += (size_t)Bb * Ls * 4;
    ka.gx1   = ws + off; off += (size_t)Bb * Ls;
    ka.gx2   = ws + off; off += (size_t)Bb * Ls;
    ka.awb   = ws + off; off += (size_t)Bb * Ls;

    k_init<<<512, NTHR, 0, stream>>>(ka);
    mega<<<GRID, NTHR, 0, stream>>>(ka);
}